// Round 6
// baseline (12258.484 us; speedup 1.0000x reference)
//
#include <hip/hip_runtime.h>
#include <hip/hip_bf16.h>
#include <hip/hip_cooperative_groups.h>
#include <cstdint>
#include <cstddef>

namespace cg = cooperative_groups;

#define T_STEPS 256
#define BATCH   128
#define VOCAB   256
#define EDIM    512
#define NH      1024
#define GDIM    4096   // 4*NH
#define NST0    40     // layer0 k-steps: 8 (x) + 32 (h)
#define NST1    64     // layer1 k-steps: 32 (h0) + 32 (h1)

typedef __attribute__((ext_vector_type(8))) short short8;
typedef __attribute__((ext_vector_type(4))) float floatx4;

__device__ __forceinline__ float sigmoidf_(float x) { return 1.0f / (1.0f + __expf(-x)); }
__device__ __forceinline__ float tanhf_(float x)    { return 1.0f - 2.0f / (__expf(2.0f * x) + 1.0f); }

typedef __attribute__((address_space(1))) const unsigned int guint;
typedef __attribute__((address_space(3))) unsigned int luint;
__device__ __forceinline__ void load_lds16(const void* g, void* l) {
    // async global->LDS, 16B/lane; LDS dest = wave-uniform base + lane*16
    __builtin_amdgcn_global_load_lds((guint*)g, (luint*)l, 16, 0, 0);
}

// ---------------- fp32 GEMM (prep only: Wcomb = emb @ W0x) ----------------
#define BM 128
#define BN 128
#define BK 16
__global__ __launch_bounds__(256) void sgemm_f32(
    const float* __restrict__ A, const float* __restrict__ B,
    float* __restrict__ C, int M, int N, int K)
{
    __shared__ float As[BK][BM + 4];
    __shared__ float Bs[BK][BN + 4];
    const int tid = threadIdx.x;
    const int tr = tid >> 4, tc = tid & 15;
    const int bm = blockIdx.y, bn = blockIdx.x;
    const float* Ab = A + (size_t)bm * BM * K;
    float acc[8][8];
    #pragma unroll
    for (int i = 0; i < 8; ++i)
        #pragma unroll
        for (int j = 0; j < 8; ++j) acc[i][j] = 0.f;
    for (int k0 = 0; k0 < K; k0 += BK) {
        #pragma unroll
        for (int l = 0; l < 2; ++l) {
            int idx = tid + l * 256;
            int row = idx >> 2, c4 = idx & 3;
            float4 v = *(const float4*)(Ab + (size_t)row * K + k0 + c4 * 4);
            As[c4 * 4 + 0][row] = v.x; As[c4 * 4 + 1][row] = v.y;
            As[c4 * 4 + 2][row] = v.z; As[c4 * 4 + 3][row] = v.w;
        }
        #pragma unroll
        for (int l = 0; l < 2; ++l) {
            int idx = tid + l * 256;
            int row = idx >> 5, c4 = idx & 31;
            *(float4*)&Bs[row][c4 * 4] = *(const float4*)(B + (size_t)(k0 + row) * N + bn * BN + c4 * 4);
        }
        __syncthreads();
        #pragma unroll
        for (int kk = 0; kk < BK; ++kk) {
            float4 a0 = *(const float4*)&As[kk][tr * 8];
            float4 a1 = *(const float4*)&As[kk][tr * 8 + 4];
            float4 b0 = *(const float4*)&Bs[kk][tc * 8];
            float4 b1 = *(const float4*)&Bs[kk][tc * 8 + 4];
            float av[8] = {a0.x, a0.y, a0.z, a0.w, a1.x, a1.y, a1.z, a1.w};
            float bv[8] = {b0.x, b0.y, b0.z, b0.w, b1.x, b1.y, b1.z, b1.w};
            #pragma unroll
            for (int i = 0; i < 8; ++i)
                #pragma unroll
                for (int j = 0; j < 8; ++j) acc[i][j] += av[i] * bv[j];
        }
        __syncthreads();
    }
    #pragma unroll
    for (int i = 0; i < 8; ++i) {
        size_t row = (size_t)bm * BM + tr * 8 + i;
        #pragma unroll
        for (int j = 0; j < 8; j += 4) {
            int col = bn * BN + tc * 8 + j;
            *(float4*)(C + row * N + col) =
                make_float4(acc[i][j], acc[i][j+1], acc[i][j+2], acc[i][j+3]);
        }
    }
}

// ---------------- transpose + fp32->bf16: dst[C][R] <- src[R][C] ----------------
__global__ __launch_bounds__(256) void transpose_to_bf16(
    const float* __restrict__ src, __hip_bfloat16* __restrict__ dst, int R, int C)
{
    __shared__ float t[32][33];
    int x = blockIdx.x * 32 + threadIdx.x;
    #pragma unroll
    for (int i = 0; i < 4; ++i) {
        int y = blockIdx.y * 32 + threadIdx.y + i * 8;
        t[threadIdx.y + i * 8][threadIdx.x] = src[(size_t)y * C + x];
    }
    __syncthreads();
    int x2 = blockIdx.y * 32 + threadIdx.x;
    #pragma unroll
    for (int i = 0; i < 4; ++i) {
        int y2 = blockIdx.x * 32 + threadIdx.y + i * 8;
        dst[(size_t)y2 * R + x2] = __float2bfloat16(t[threadIdx.x][threadIdx.y + i * 8]);
    }
}

// ------- pack weights into per-(block,k-step,n-tile) 1KB fragment blocks -------
// src fp32 [Ksrc][4096] (row k, col lincol = g*1024 + n). For block j (8 hid cols),
// n-tile t (0:[f|i], 1:[o|g]), k-step s (32 k): contiguous 1KB ordered [quad][l16][8],
// so a contiguous LDS copy IS the MFMA B-fragment layout (lane reads at lane*16B).
__global__ __launch_bounds__(256) void pack_w2(
    const float* __restrict__ src, __hip_bfloat16* __restrict__ dst,
    int koff, int NSTEPS)
{
    __shared__ float t[64][33];
    const int tid = threadIdx.x;
    const int xt = blockIdx.x;   // lincol tile of 64
    const int kt = blockIdx.y;   // k tile of 32
    {   // load 32k x 64lincol tile, coalesced, store transposed
        int yl = tid >> 3;                 // 0..31 k-local
        int x0 = (tid & 7) * 8;            // 0..56 lincol-local
        const float* p = src + (size_t)(kt * 32 + yl) * GDIM + xt * 64 + x0;
        float4 v0 = *(const float4*)p;
        float4 v1 = *(const float4*)(p + 4);
        t[x0 + 0][yl] = v0.x; t[x0 + 1][yl] = v0.y; t[x0 + 2][yl] = v0.z; t[x0 + 3][yl] = v0.w;
        t[x0 + 4][yl] = v1.x; t[x0 + 5][yl] = v1.y; t[x0 + 6][yl] = v1.z; t[x0 + 7][yl] = v1.w;
    }
    __syncthreads();
    {   // write: thread = (lincol_local, quad) -> 16B of 8 k-consecutive bf16
        int ll = tid >> 2;                 // 0..63
        int quad = tid & 3;
        int lincol = xt * 64 + ll;
        int g = lincol >> 10, n = lincol & 1023;
        int j = n >> 3, c = n & 7;
        int tt = g >> 1;
        int l16 = (g & 1) * 8 + c;
        int s = (koff >> 5) + kt;
        __hip_bfloat16 o[8];
        #pragma unroll
        for (int jj = 0; jj < 8; ++jj)
            o[jj] = __float2bfloat16(t[ll][quad * 8 + jj]);
        size_t off = ((((size_t)j * NSTEPS + s) * 2 + tt) * 64 + (size_t)quad * 16 + l16) * 8;
        *(uint4*)(dst + off) = *(const uint4*)o;
    }
}

// ---------------- fp32 -> bf16 convert ----------------
__global__ __launch_bounds__(256) void convert_to_bf16(
    const float* __restrict__ src, __hip_bfloat16* __restrict__ dst, size_t n4)
{
    size_t i = (size_t)blockIdx.x * 256 + threadIdx.x;
    if (i < n4) {
        float4 v = *(const float4*)(src + i * 4);
        __hip_bfloat16 o[4] = {__float2bfloat16(v.x), __float2bfloat16(v.y),
                               __float2bfloat16(v.z), __float2bfloat16(v.w)};
        *(uint2*)(dst + i * 4) = *(uint2*)o;
    }
}

// ---------------- bf16 MFMA GEMM: C[M][N] f32 = A[M][K] @ Bt[N][K] (+bias) ------
#define GKP 40
__global__ __launch_bounds__(256) void gemm_bt(
    const __hip_bfloat16* __restrict__ A, const __hip_bfloat16* __restrict__ Bt,
    const float* __restrict__ bias, float* __restrict__ C, int M, int N, int K)
{
    __shared__ __hip_bfloat16 As[128 * GKP];
    __shared__ __hip_bfloat16 Bs[128 * GKP];
    const int tid = threadIdx.x;
    const int wave = tid >> 6, lane = tid & 63;
    const int quad = lane >> 4, l16 = lane & 15;
    const int wm = (wave >> 1) * 64, wn = (wave & 1) * 64;
    const size_t Arow0 = (size_t)blockIdx.y * 128;
    const size_t Brow0 = (size_t)blockIdx.x * 128;
    floatx4 acc[4][4];
    #pragma unroll
    for (int i = 0; i < 4; ++i)
        #pragma unroll
        for (int j = 0; j < 4; ++j) acc[i][j] = (floatx4)0.f;

    for (int k0 = 0; k0 < K; k0 += 32) {
        #pragma unroll
        for (int l = 0; l < 2; ++l) {
            int idx = tid + l * 256;
            int row = idx >> 2, seg = idx & 3;
            *(uint4*)(As + row * GKP + seg * 8) =
                *(const uint4*)(A + (Arow0 + row) * K + k0 + seg * 8);
            *(uint4*)(Bs + row * GKP + seg * 8) =
                *(const uint4*)(Bt + (Brow0 + row) * K + k0 + seg * 8);
        }
        __syncthreads();
        short8 af[4], bf[4];
        #pragma unroll
        for (int i = 0; i < 4; ++i)
            af[i] = *(const short8*)(As + (wm + i * 16 + l16) * GKP + quad * 8);
        #pragma unroll
        for (int j = 0; j < 4; ++j)
            bf[j] = *(const short8*)(Bs + (wn + j * 16 + l16) * GKP + quad * 8);
        #pragma unroll
        for (int i = 0; i < 4; ++i)
            #pragma unroll
            for (int j = 0; j < 4; ++j)
                acc[i][j] = __builtin_amdgcn_mfma_f32_16x16x32_bf16(af[i], bf[j], acc[i][j], 0, 0, 0);
        __syncthreads();
    }
    #pragma unroll
    for (int i = 0; i < 4; ++i)
        #pragma unroll
        for (int j = 0; j < 4; ++j) {
            int col = (int)Brow0 + wn + j * 16 + l16;
            float bv = bias ? bias[col] : 0.f;
            #pragma unroll
            for (int r = 0; r < 4; ++r) {
                size_t row = Arow0 + wm + i * 16 + quad * 4 + r;
                C[row * N + col] = acc[i][j][r] + bv;
            }
        }
}

// ---------------- persistent diagonal LSTM (cooperative) ----------------
// One launch for the entire recurrence. 256 blocks: even=layer0, odd=layer1.
// Block owns 8 hid cols (2 n-tiles [f|i],[o|g]); 512 threads = 8 waves, wave w
// owns batch rows [16w,16w+16). A: per-lane direct global loads (no LDS).
// B: 16KB chunks staged via contiguous global_load_lds, double-buffered.
// c-state lives in registers across all timesteps. grid.sync() between steps.
__global__ __launch_bounds__(512) void lstm_persist(
    const __hip_bfloat16* __restrict__ inbf,   // [256][128][256]
    const __hip_bfloat16* __restrict__ Wpack0, // [128][40][2][1KB]
    const __hip_bfloat16* __restrict__ Wpack1, // [128][64][2][1KB]
    const float* __restrict__ b0, const float* __restrict__ b1,
    __hip_bfloat16* __restrict__ h0a,          // h0 ping-pong: buf[t&1]
    __hip_bfloat16* __restrict__ h0b,
    __hip_bfloat16* __restrict__ H1all)        // [256][128][1024]
{
    cg::grid_group grid = cg::this_grid();
    const int layer = blockIdx.x & 1;
    const int j = blockIdx.x >> 1;

    __shared__ __attribute__((aligned(16))) __hip_bfloat16 Bbuf[2][8192]; // 2 x 16KB

    const int tid = threadIdx.x;
    const int wave = tid >> 6, lane = tid & 63;
    const int quad = lane >> 4, l16 = lane & 15;
    const int row = wave * 16 + l16;
    const int cc = j * 8 + (l16 & 7);

    const float* bb = layer ? b1 : b0;
    const float bv0 = bb[((l16 < 8) ? 0 : 1) * NH + cc];
    const float bv1 = bb[((l16 < 8) ? 2 : 3) * NH + cc];
    const __hip_bfloat16* Wp = layer ? (Wpack1 + (size_t)j * (NST1 * 1024))
                                     : (Wpack0 + (size_t)j * (NST0 * 1024));
    float creg[4] = {0.f, 0.f, 0.f, 0.f};

    for (int d = 0; d <= T_STEPS; ++d) {
        const bool active = layer ? (d >= 1) : (d < T_STEPS);
        if (active) {
            __hip_bfloat16* h0cur  = (d & 1) ? h0b : h0a;       // h0[d]
            __hip_bfloat16* h0prev = (d & 1) ? h0a : h0b;       // h0[d-1]
            const __hip_bfloat16 *A0, *A1;
            int A0stride, NC, NCA0;
            __hip_bfloat16* hout;
            if (layer == 0) {
                NC = (d == 0) ? 1 : 5; NCA0 = 1;
                A0 = inbf + (size_t)d * (BATCH * VOCAB); A0stride = VOCAB;
                A1 = h0prev;
                hout = h0cur;
            } else {
                NC = (d == 1) ? 4 : 8; NCA0 = 4;
                A0 = h0prev; A0stride = NH;
                A1 = (d >= 2) ? (H1all + (size_t)(d - 2) * (BATCH * NH)) : h0prev;
                hout = H1all + (size_t)(d - 1) * (BATCH * NH);
            }
            const __hip_bfloat16* pA0 = A0 + (size_t)row * A0stride + quad * 8;
            const __hip_bfloat16* pA1 = A1 + (size_t)row * NH + quad * 8;

            #define STAGE(c, b) do { \
                const __hip_bfloat16* g0_ = Wp + (size_t)(c) * 8192 + wave * 512 + lane * 8; \
                load_lds16(g0_, &Bbuf[b][wave * 512]); \
                load_lds16(g0_ + 8 * 512, &Bbuf[b][(wave + 8) * 512]); \
            } while (0)

            floatx4 acc0 = {bv0, bv0, bv0, bv0};
            floatx4 acc1 = {bv1, bv1, bv1, bv1};

            STAGE(0, 0);
            __syncthreads();
            for (int c = 0; c < NC; ++c) {
                const int cur = c & 1, nxt = cur ^ 1;
                // A loads first (so MFMA's waitcnt leaves the prefetch in flight)
                const __hip_bfloat16* pa = (c < NCA0) ? (pA0 + (size_t)c * 8 * 32)
                                                      : (pA1 + (size_t)(c - NCA0) * 8 * 32);
                short8 af[8];
                #pragma unroll
                for (int ss = 0; ss < 8; ++ss)
                    af[ss] = *(const short8*)(pa + ss * 32);
                if (c + 1 < NC) STAGE(c + 1, nxt);
                #pragma unroll
                for (int ss = 0; ss < 8; ++ss) {
                    short8 bf0 = *(const short8*)&Bbuf[cur][(ss * 2 + 0) * 512 + lane * 8];
                    short8 bf1 = *(const short8*)&Bbuf[cur][(ss * 2 + 1) * 512 + lane * 8];
                    acc0 = __builtin_amdgcn_mfma_f32_16x16x32_bf16(af[ss], bf0, acc0, 0, 0, 0);
                    acc1 = __builtin_amdgcn_mfma_f32_16x16x32_bf16(af[ss], bf1, acc1, 0, 0, 0);
                }
                __syncthreads();
            }
            #undef STAGE

            // epilogue: lanes l16<8 hold (f,o), lanes l16>=8 hold (i,g) for col cc
            #pragma unroll
            for (int r = 0; r < 4; ++r) {
                float a0 = acc0[r], a1 = acc1[r];
                float p0 = __shfl_xor(a0, 8, 64);
                float p1 = __shfl_xor(a1, 8, 64);
                if (l16 < 8) {
                    int b = 16 * wave + quad * 4 + r;
                    float f  = sigmoidf_(a0);
                    float ig = sigmoidf_(p0);
                    float oo = sigmoidf_(a1);
                    float gg = tanhf_(p1);
                    float cn = f * creg[r] + ig * gg;
                    float hn = oo * tanhf_(cn);
                    creg[r] = cn;
                    hout[(size_t)b * NH + cc] = __float2bfloat16(hn);
                }
            }
        }
        grid.sync();
    }
}

extern "C" void kernel_launch(void* const* d_in, const int* in_sizes, int n_in,
                              void* d_out, int out_size, void* d_ws, size_t ws_size,
                              hipStream_t stream)
{
    const float* inputs = (const float*)d_in[0];  // [256,128,256]
    const float* emb    = (const float*)d_in[1];  // [256,512]
    const float* w0     = (const float*)d_in[2];  // [1536,4096]
    const float* b0     = (const float*)d_in[3];  // [4096]
    const float* w1     = (const float*)d_in[4];  // [2048,4096]
    const float* b1     = (const float*)d_in[5];  // [4096]
    const float* outw   = (const float*)d_in[6];  // [1024,256]
    const float* outb   = (const float*)d_in[7];  // [256]
    float* out = (float*)d_out;                   // [32768,256]

    char* ws = (char*)d_ws;
    size_t off = 0;
    auto take = [&](size_t bytes) { char* p = ws + off; off += (bytes + 255) & ~(size_t)255; return p; };
    float* Wcomb = (float*)take((size_t)VOCAB * GDIM * 4);                          // 4 MB
    __hip_bfloat16* Wpack0 = (__hip_bfloat16*)take((size_t)128 * NST0 * 1024 * 2);  // 10 MB
    __hip_bfloat16* Wpack1 = (__hip_bfloat16*)take((size_t)128 * NST1 * 1024 * 2);  // 16 MB
    __hip_bfloat16* outwt  = (__hip_bfloat16*)take((size_t)NH * VOCAB * 2);         // 0.5 MB
    __hip_bfloat16* inbf   = (__hip_bfloat16*)take((size_t)T_STEPS * BATCH * VOCAB * 2); // 16 MB
    __hip_bfloat16* h0a    = (__hip_bfloat16*)take((size_t)BATCH * NH * 2);
    __hip_bfloat16* h0b    = (__hip_bfloat16*)take((size_t)BATCH * NH * 2);
    __hip_bfloat16* H1all  = (__hip_bfloat16*)take((size_t)T_STEPS * BATCH * NH * 2); // 64 MB

    // ---- prep ----
    sgemm_f32<<<dim3(GDIM / BN, VOCAB / BM), 256, 0, stream>>>(
        emb, w0, Wcomb, VOCAB, GDIM, EDIM);
    // layer-0: [Wcomb (k 0..255) | W0h (k 256..1279)]
    pack_w2<<<dim3(64, VOCAB / 32), 256, 0, stream>>>(Wcomb, Wpack0, 0, NST0);
    pack_w2<<<dim3(64, NH / 32), 256, 0, stream>>>(w0 + (size_t)EDIM * GDIM, Wpack0, VOCAB, NST0);
    // layer-1: [W1x (k 0..1023) | W1h (k 1024..2047)]
    pack_w2<<<dim3(64, NH / 32), 256, 0, stream>>>(w1, Wpack1, 0, NST1);
    pack_w2<<<dim3(64, NH / 32), 256, 0, stream>>>(w1 + (size_t)NH * GDIM, Wpack1, NH, NST1);
    // out_w -> bf16 n-major
    transpose_to_bf16<<<dim3(VOCAB / 32, NH / 32), dim3(32, 8), 0, stream>>>(
        outw, outwt, NH, VOCAB);
    // inputs -> bf16
    {
        size_t n4 = (size_t)T_STEPS * BATCH * VOCAB / 4;
        convert_to_bf16<<<(int)((n4 + 255) / 256), 256, 0, stream>>>(inputs, inbf, n4);
    }

    // ---- recurrence: ONE cooperative dispatch ----
    {
        void* args[] = {(void*)&inbf, (void*)&Wpack0, (void*)&Wpack1,
                        (void*)&b0, (void*)&b1,
                        (void*)&h0a, (void*)&h0b, (void*)&H1all};
        hipLaunchCooperativeKernel((const void*)lstm_persist,
                                   dim3(256), dim3(512), args, 0, stream);
    }

    // ---- logits = H1 @ out_w + out_b ----
    gemm_bt<<<dim3(VOCAB / 128, (T_STEPS * BATCH) / 128), 256, 0, stream>>>(
        H1all, outwt, outb, out, T_STEPS * BATCH, VOCAB, NH);
}